// Round 18
// baseline (212.640 us; speedup 1.0000x reference)
//
#include <hip/hip_runtime.h>
#include <hip/hip_bf16.h>

#define TOKENS 8192
#define KDIM 1024
#define NDIM 1024
#define NEXP 8

typedef __attribute__((ext_vector_type(8))) short short8v;
typedef __attribute__((ext_vector_type(8))) unsigned short ushort8v;
typedef __attribute__((ext_vector_type(4))) float f32x4;

__device__ inline unsigned short f2bf(float f) {
  unsigned int u = __float_as_uint(f);
  u += 0x7fffu + ((u >> 16) & 1u);
  return (unsigned short)(u >> 16);
}

__device__ inline void gload_lds16(const void* g, void* l) {
  __builtin_amdgcn_global_load_lds(
      (const __attribute__((address_space(1))) unsigned int*)g,
      (__attribute__((address_space(3))) unsigned int*)l, 16, 0, 0);
}

// ============================ FAST PATH ============================

// Fused: [0,256) gating + x->bf16; [256,4352) We->bf16; [4352,5376) zero out
// (zero blocks only launched on the mid/atomic path).
__global__ __launch_bounds__(256) void gate_conv_kernel(
    const float* __restrict__ x, const float* __restrict__ Wg,
    const float* __restrict__ bg, const float* __restrict__ We,
    unsigned short* __restrict__ xb, unsigned short* __restrict__ Web,
    int* __restrict__ epacked, float2* __restrict__ wpair,
    int* __restrict__ hist, float* __restrict__ out) {
  int b = blockIdx.x;
  int tid = threadIdx.x;
  if (b >= 4352) {
    float4* o = reinterpret_cast<float4*>(out) + (size_t)(b - 4352) * 2048 + tid;
    float4 z = make_float4(0.f, 0.f, 0.f, 0.f);
#pragma unroll
    for (int i = 0; i < 8; ++i) o[i * 256] = z;
    return;
  }
  if (b >= 256) {
    size_t i = (size_t)(b - 256) * 256 + tid;
    const float4* s = reinterpret_cast<const float4*>(We + i * 8);
    float4 a = s[0], c = s[1];
    ushort8v v;
    v[0] = f2bf(a.x); v[1] = f2bf(a.y); v[2] = f2bf(a.z); v[3] = f2bf(a.w);
    v[4] = f2bf(c.x); v[5] = f2bf(c.y); v[6] = f2bf(c.z); v[7] = f2bf(c.w);
    *reinterpret_cast<ushort8v*>(Web + i * 8) = v;
    return;
  }
  __shared__ int lhist[16];
  if (tid < 16) lhist[tid] = 0;
  __syncthreads();
  int w = tid >> 6, lane = tid & 63;
  int tok0 = b * 32 + w * 8;

  for (int t = 0; t < 8; ++t) {
    int tok = tok0 + t;
    const float* xr = x + (size_t)tok * KDIM + lane * 16;
    float acc[NEXP] = {};
    ushort8v xv0, xv1;
#pragma unroll
    for (int j4 = 0; j4 < 4; ++j4) {
      float4 xv = *reinterpret_cast<const float4*>(xr + j4 * 4);
      float xs[4] = {xv.x, xv.y, xv.z, xv.w};
#pragma unroll
      for (int jj = 0; jj < 4; ++jj) {
        int k = lane * 16 + j4 * 4 + jj;
        const float4* wr = reinterpret_cast<const float4*>(Wg + k * NEXP);
        float4 w0 = wr[0], w1 = wr[1];
        float xf = xs[jj];
        acc[0] += xf * w0.x; acc[1] += xf * w0.y;
        acc[2] += xf * w0.z; acc[3] += xf * w0.w;
        acc[4] += xf * w1.x; acc[5] += xf * w1.y;
        acc[6] += xf * w1.z; acc[7] += xf * w1.w;
        int li = j4 * 4 + jj;
        unsigned short bv = f2bf(xf);
        if (li < 8) xv0[li] = bv; else xv1[li - 8] = bv;
      }
    }
    unsigned short* xrow = xb + (size_t)tok * KDIM + lane * 16;
    *reinterpret_cast<ushort8v*>(xrow) = xv0;
    *reinterpret_cast<ushort8v*>(xrow + 8) = xv1;
#pragma unroll
    for (int e = 0; e < NEXP; ++e) {
      acc[e] += __shfl_xor(acc[e], 1, 64);
      acc[e] += __shfl_xor(acc[e], 2, 64);
      acc[e] += __shfl_xor(acc[e], 4, 64);
      acc[e] += __shfl_xor(acc[e], 8, 64);
      acc[e] += __shfl_xor(acc[e], 16, 64);
      acc[e] += __shfl_xor(acc[e], 32, 64);
    }
    if (lane == 0) {
      float lg[NEXP];
#pragma unroll
      for (int e = 0; e < NEXP; ++e) lg[e] = acc[e] + bg[e];
      int e0 = 0;
#pragma unroll
      for (int e = 1; e < NEXP; ++e) if (lg[e] > lg[e0]) e0 = e;
      int e1 = -1;
#pragma unroll
      for (int e = 0; e < NEXP; ++e) {
        if (e == e0) continue;
        if (e1 < 0 || lg[e] > lg[e1]) e1 = e;
      }
      float tv = expf(lg[e1] - lg[e0]);
      float w0 = 1.0f / (1.0f + tv);
      float w1 = tv * w0;
      epacked[tok] = e0 | (e1 << 8);
      wpair[tok] = make_float2(w0, w1);
      atomicAdd(&lhist[e0], 1);
      atomicAdd(&lhist[8 + e1], 1);
    }
  }
  __syncthreads();
  if (tid < 16) hist[b * 16 + tid] = lhist[tid];
}

// scatter: per-block exclusive prefix over histograms -> routed lists.
__global__ __launch_bounds__(256) void scatter_kernel(
    const int* __restrict__ hist, const int* __restrict__ epacked,
    const float2* __restrict__ wpair, int* __restrict__ counts,
    int* __restrict__ lists, float* __restrict__ wlists) {
  __shared__ int partial[16][17];
  __shared__ int base[16];
  __shared__ int cnt2[16];
  int tid = threadIdx.x;
  int b = blockIdx.x;
  int bin = tid & 15, grp = tid >> 4;
  int s = 0;
  for (int i = 0; i < 16; ++i) {
    int bb = grp * 16 + i;
    if (bb < b) s += hist[bb * 16 + bin];
  }
  partial[grp][bin] = s;
  if (tid < 16) cnt2[tid] = 0;
  __syncthreads();
  if (tid < 16) {
    int s2 = 0;
#pragma unroll
    for (int g = 0; g < 16; ++g) s2 += partial[g][tid];
    base[tid] = s2;
  }
  __syncthreads();
  if (tid < 64) {
    int tok = b * 32 + (tid >> 1);
    int slot = tid & 1;
    int ep = epacked[tok];
    int e = slot ? ((ep >> 8) & 255) : (ep & 255);
    float2 wp = wpair[tok];
    float wv = slot ? wp.y : wp.x;
    int bn = slot * 8 + e;
    int pos = base[bn] + atomicAdd(&cnt2[bn], 1);
    lists[bn * TOKENS + pos] = tok;
    wlists[bn * TOKENS + pos] = wv;
  }
  if (b == 255) {
    __syncthreads();
    if (tid < 16) counts[tid] = base[tid] + cnt2[tid];
  }
}

// NO-LDS grouped GEMM: 64M x 256N per block, 256 thr / 4 waves (1M x 4N),
// wave 64x64 out, acc[4][4] (proven spill-free). Fragments loaded DIRECTLY
// from L1/L2 into VGPRs — no LDS, no barriers, no vmcnt(0) drains.
// WHY: r17 proved the staged kernel is NOT BW-bound (FETCH 99->39MB, time
// unchanged) — the serial barrier-drain convoy is the wall. B panel is
// L2-resident via XCD pinning (id&7=e, m09 round-robin); A rows ~2MB/XCD.
// Catalog common-mistake #7: don't LDS-stage what L2 fits.
// Frag layout = exactly what the LDS path read: 8 contiguous bf16 at
// [row][kt*32 + lk*8]; wave covers 16 rows x 64B per load (coalesced).
template <int PLAIN>
__global__ __launch_bounds__(256) void moe_gemm_nolds(
    const unsigned short* __restrict__ xb, const unsigned short* __restrict__ Web,
    const float* __restrict__ be, const int* __restrict__ counts,
    const int* __restrict__ lists, const float* __restrict__ wlists,
    float* __restrict__ out, float* __restrict__ p1) {
  int id = blockIdx.x;           // 2048 flat blocks
  int e = id & 7;                // XCD-pinned expert
  int rest = id >> 3;
  int slot = rest & 1;
  int bx = (rest >> 1) & 3;      // N-tile (256 wide)
  int by = rest >> 3;            // M-tile 0..31 (64 rows)
  int bz = slot * 8 + e;
  int cnt = counts[bz];
  int mbase = by * 64;
  if (mbase >= cnt) return;
  int nbase = bx * 256;
  const int* lst = lists + bz * TOKENS;
  const float* wl = wlists + bz * TOKENS;

  int lane = threadIdx.x & 63;
  int w = threadIdx.x >> 6;      // wave 0..3 = N-quarter
  int lm = lane & 15, lk = lane >> 4;

  // A row pointers (token-gathered); all 4 waves share the same 64 rows (L1 reuse)
  const unsigned short* arow[4];
#pragma unroll
  for (int mi = 0; mi < 4; ++mi) {
    int gr = mbase + mi * 16 + lm;
    if (gr >= cnt) gr = cnt - 1;
    arow[mi] = xb + (size_t)lst[gr] * KDIM + lk * 8;
  }
  // B row pointers: rows nbase + w*64 + nj*16 + lm (L2-resident panel)
  const unsigned short* brow[4];
#pragma unroll
  for (int nj = 0; nj < 4; ++nj)
    brow[nj] = Web + (size_t)e * (NDIM * KDIM) +
               (size_t)(nbase + w * 64 + nj * 16 + lm) * KDIM + lk * 8;

  f32x4 acc[4][4] = {};
#pragma unroll 4
  for (int kt = 0; kt < 32; ++kt) {  // K=32 per step
    short8v af[4], bfv[4];
#pragma unroll
    for (int mi = 0; mi < 4; ++mi)
      af[mi] = *reinterpret_cast<const short8v*>(arow[mi] + kt * 32);
#pragma unroll
    for (int nj = 0; nj < 4; ++nj)
      bfv[nj] = *reinterpret_cast<const short8v*>(brow[nj] + kt * 32);
#pragma unroll
    for (int mi = 0; mi < 4; ++mi)
#pragma unroll
      for (int nj = 0; nj < 4; ++nj)
        acc[mi][nj] = __builtin_amdgcn_mfma_f32_16x16x32_bf16(
            af[mi], bfv[nj], acc[mi][nj], 0, 0, 0);
  }

  // epilogue: C/D mapping col=lane&15, row=(lane>>4)*4+reg  [m89/m91]
  float* dst = (PLAIN && slot) ? p1 : out;
  float bev[4];
#pragma unroll
  for (int nj = 0; nj < 4; ++nj)
    bev[nj] = be[e * NDIM + nbase + w * 64 + nj * 16 + lm];
#pragma unroll
  for (int mi = 0; mi < 4; ++mi) {
#pragma unroll
    for (int r = 0; r < 4; ++r) {
      int grow = mbase + mi * 16 + lk * 4 + r;
      if (grow >= cnt) continue;
      int tokn = lst[grow];
      float wgt = wl[grow];
      float* orow = dst + (size_t)tokn * NDIM + nbase + w * 64 + lm;
#pragma unroll
      for (int nj = 0; nj < 4; ++nj) {
        float val = wgt * (acc[mi][nj][r] + bev[nj]);
        if (PLAIN) orow[nj * 16] = val;
        else       unsafeAtomicAdd(&orow[nj * 16], val);
      }
    }
  }
}

// out += p1 (both full disjoint single-writer covers)
__global__ __launch_bounds__(256) void combine_kernel(
    float* __restrict__ out, const float* __restrict__ p1) {
  size_t i = (size_t)blockIdx.x * 256 + threadIdx.x;
  float4 a = reinterpret_cast<const float4*>(p1)[i];
  float4 b = reinterpret_cast<float4*>(out)[i];
  b.x += a.x; b.y += a.y; b.z += a.z; b.w += a.w;
  reinterpret_cast<float4*>(out)[i] = b;
}

// ============================ MID PATH (r17 proven, atomic) ============================

__global__ __launch_bounds__(512) void moe_gemm_wide(
    const unsigned short* __restrict__ xb, const unsigned short* __restrict__ Web,
    const float* __restrict__ be, const int* __restrict__ counts,
    const int* __restrict__ lists, const float* __restrict__ wlists,
    float* __restrict__ out) {
  int id = blockIdx.x;
  int e = id & 7;
  int rest = id >> 3;
  int slot = rest & 1;
  int bx = (rest >> 1) & 3;
  int by = rest >> 3;
  int bz = slot * 8 + e;
  int cnt = counts[bz];
  int mbase = by * 64;
  if (mbase >= cnt) return;
  int nbase = bx * 256;
  const int* lst = lists + bz * TOKENS;
  const float* wl = wlists + bz * TOKENS;
  __shared__ alignas(128) unsigned short lA[64 * 64];
  __shared__ alignas(128) unsigned short lB[256 * 64];
  int tid = threadIdx.x;
  int lane = tid & 63;
  int w = tid >> 6;
  int wm = w >> 2, wn = w & 3;
  int lm = lane & 15, lk = lane >> 4;
  const unsigned short* aga;
  {
    int r = tid >> 3, cs = tid & 7;
    int c = cs ^ (r & 7);
    int gr = mbase + r; if (gr >= cnt) gr = cnt - 1;
    aga = xb + (size_t)lst[gr] * KDIM + c * 8;
  }
  const unsigned short* bga[4];
#pragma unroll
  for (int j = 0; j < 4; ++j) {
    int L = j * 512 + tid;
    int r = L >> 3, cs = L & 7;
    int c = cs ^ (r & 7);
    bga[j] = Web + (size_t)e * (NDIM * KDIM) + (size_t)(nbase + r) * KDIM + c * 8;
  }
#define STAGE(kt)                                                             \
  {                                                                           \
    gload_lds16(aga + (kt) * 64, (char*)lA + w * 1024);                       \
    _Pragma("unroll") for (int j = 0; j < 4; ++j)                             \
      gload_lds16(bga[j] + (kt) * 64, (char*)lB + j * 8192 + w * 1024);       \
  }
  f32x4 acc[2][4] = {};
#define COMPUTE                                                               \
  {                                                                           \
    _Pragma("unroll") for (int ks = 0; ks < 2; ++ks) {                        \
      short8v af[2], bfv[4];                                                  \
      _Pragma("unroll") for (int mi = 0; mi < 2; ++mi) {                      \
        int row = wm * 32 + mi * 16 + lm;                                     \
        int cs = (ks * 4 + lk) ^ (row & 7);                                   \
        af[mi] = *reinterpret_cast<const short8v*>(&lA[row * 64 + cs * 8]);   \
      }                                                                       \
      _Pragma("unroll") for (int nj = 0; nj < 4; ++nj) {                      \
        int row = wn * 64 + nj * 16 + lm;                                     \
        int cs = (ks * 4 + lk) ^ (row & 7);                                   \
        bfv[nj] = *reinterpret_cast<const short8v*>(&lB[row * 64 + cs * 8]);  \
      }                                                                       \
      _Pragma("unroll") for (int mi = 0; mi < 2; ++mi)                        \
        _Pragma("unroll") for (int nj = 0; nj < 4; ++nj)                      \
          acc[mi][nj] = __builtin_amdgcn_mfma_f32_16x16x32_bf16(              \
              af[mi], bfv[nj], acc[mi][nj], 0, 0, 0);                         \
    }                                                                         \
  }
  for (int kt = 0; kt < 16; ++kt) {
    __syncthreads();
    STAGE(kt);
    __syncthreads();
    COMPUTE;
  }
#undef STAGE
#undef COMPUTE
  float bev[4];
#pragma unroll
  for (int nj = 0; nj < 4; ++nj)
    bev[nj] = be[e * NDIM + nbase + wn * 64 + nj * 16 + lm];
#pragma unroll
  for (int mi = 0; mi < 2; ++mi) {
#pragma unroll
    for (int r = 0; r < 4; ++r) {
      int grow = mbase + wm * 32 + mi * 16 + lk * 4 + r;
      if (grow >= cnt) continue;
      int tokn = lst[grow];
      float wgt = wl[grow];
      float* orow = out + (size_t)tokn * NDIM + nbase + wn * 64 + lm;
#pragma unroll
      for (int nj = 0; nj < 4; ++nj)
        unsafeAtomicAdd(&orow[nj * 16], wgt * (acc[mi][nj][r] + bev[nj]));
    }
  }
}

// ============================ DEEP FALLBACK (round-1) ============================

__global__ __launch_bounds__(256) void gate_kernel(
    const float* __restrict__ x, const float* __restrict__ Wg,
    const float* __restrict__ bg, int* __restrict__ counts,
    int* __restrict__ lists, float* __restrict__ wlists) {
  int gtid = blockIdx.x * blockDim.x + threadIdx.x;
  int tok = gtid >> 6;
  int lane = threadIdx.x & 63;
  if (tok >= TOKENS) return;
  const float* xr = x + (size_t)tok * KDIM + lane * 16;
  float acc[NEXP] = {};
#pragma unroll
  for (int j4 = 0; j4 < 4; ++j4) {
    float4 xv = *reinterpret_cast<const float4*>(xr + j4 * 4);
    float xs[4] = {xv.x, xv.y, xv.z, xv.w};
#pragma unroll
    for (int jj = 0; jj < 4; ++jj) {
      int k = lane * 16 + j4 * 4 + jj;
      const float4* wr = reinterpret_cast<const float4*>(Wg + k * NEXP);
      float4 w0 = wr[0], w1 = wr[1];
      float xv1 = xs[jj];
      acc[0] += xv1 * w0.x; acc[1] += xv1 * w0.y;
      acc[2] += xv1 * w0.z; acc[3] += xv1 * w0.w;
      acc[4] += xv1 * w1.x; acc[5] += xv1 * w1.y;
      acc[6] += xv1 * w1.z; acc[7] += xv1 * w1.w;
    }
  }
#pragma unroll
  for (int e = 0; e < NEXP; ++e) {
    acc[e] += __shfl_xor(acc[e], 1, 64);
    acc[e] += __shfl_xor(acc[e], 2, 64);
    acc[e] += __shfl_xor(acc[e], 4, 64);
    acc[e] += __shfl_xor(acc[e], 8, 64);
    acc[e] += __shfl_xor(acc[e], 16, 64);
    acc[e] += __shfl_xor(acc[e], 32, 64);
  }
  if (lane == 0) {
    float lg[NEXP];
#pragma unroll
    for (int e = 0; e < NEXP; ++e) lg[e] = acc[e] + bg[e];
    int e0 = 0;
#pragma unroll
    for (int e = 1; e < NEXP; ++e) if (lg[e] > lg[e0]) e0 = e;
    int e1 = -1;
#pragma unroll
    for (int e = 0; e < NEXP; ++e) {
      if (e == e0) continue;
      if (e1 < 0 || lg[e] > lg[e1]) e1 = e;
    }
    float t = expf(lg[e1] - lg[e0]);
    float w0 = 1.0f / (1.0f + t);
    float w1 = t * w0;
    int p0 = atomicAdd(&counts[e0], 1);
    lists[e0 * TOKENS + p0] = tok;
    wlists[e0 * TOKENS + p0] = w0;
    int p1 = atomicAdd(&counts[NEXP + e1], 1);
    lists[(NEXP + e1) * TOKENS + p1] = tok;
    wlists[(NEXP + e1) * TOKENS + p1] = w1;
  }
}

template <int ACCUM>
__global__ __launch_bounds__(256) void moe_gemm(
    const float* __restrict__ x, const float* __restrict__ We,
    const float* __restrict__ be, const int* __restrict__ counts,
    const int* __restrict__ lists, const float* __restrict__ wlists,
    float* __restrict__ out, int slot) {
  int e = blockIdx.z;
  int cnt = counts[slot * NEXP + e];
  int mbase = blockIdx.y * 128;
  if (mbase >= cnt) return;
  int nbase = blockIdx.x * 128;
  const int* lst = lists + (slot * NEXP + e) * TOKENS;
  const float* wl = wlists + (slot * NEXP + e) * TOKENS;
  __shared__ ushort8v lA[1024];
  __shared__ ushort8v lB[1024];
  int tid = threadIdx.x;
  int lane = tid & 63;
  int w = tid >> 6;
  int wm = w >> 1, wn = w & 1;
  const float* aptr[4];
  const float* bptr[4];
  int sw[4];
#pragma unroll
  for (int i = 0; i < 4; ++i) {
    int c = i * 256 + tid;
    int r = c >> 3, cc = c & 7;
    int gr = mbase + r;
    if (gr >= cnt) gr = cnt - 1;
    int tokn = lst[gr];
    aptr[i] = x + (size_t)tokn * KDIM + cc * 8;
    bptr[i] = We + (size_t)e * (NDIM * KDIM) + (size_t)(nbase + r) * KDIM + cc * 8;
    sw[i] = r * 8 + (cc ^ (r & 7));
  }
  f32x4 acc[4][4] = {};
  int lm = lane & 15, lk = lane >> 4;
  for (int kt = 0; kt < KDIM / 64; ++kt) {
    __syncthreads();
#pragma unroll
    for (int i = 0; i < 4; ++i) {
      float4 f0 = *reinterpret_cast<const float4*>(aptr[i] + kt * 64);
      float4 f1 = *reinterpret_cast<const float4*>(aptr[i] + kt * 64 + 4);
      ushort8v v;
      v[0] = f2bf(f0.x); v[1] = f2bf(f0.y); v[2] = f2bf(f0.z); v[3] = f2bf(f0.w);
      v[4] = f2bf(f1.x); v[5] = f2bf(f1.y); v[6] = f2bf(f1.z); v[7] = f2bf(f1.w);
      lA[sw[i]] = v;
      float4 g0 = *reinterpret_cast<const float4*>(bptr[i] + kt * 64);
      float4 g1 = *reinterpret_cast<const float4*>(bptr[i] + kt * 64 + 4);
      ushort8v u;
      u[0] = f2bf(g0.x); u[1] = f2bf(g0.y); u[2] = f2bf(g0.z); u[3] = f2bf(g0.w);
      u[4] = f2bf(g1.x); u[5] = f2bf(g1.y); u[6] = f2bf(g1.z); u[7] = f2bf(g1.w);
      lB[sw[i]] = u;
    }
    __syncthreads();
#pragma unroll
    for (int ks = 0; ks < 2; ++ks) {
      short8v af[4], bfv[4];
#pragma unroll
      for (int mi = 0; mi < 4; ++mi) {
        int row = wm * 64 + mi * 16 + lm;
        int cidx = (ks * 4 + lk) ^ (row & 7);
        af[mi] = *reinterpret_cast<const short8v*>(&lA[row * 8 + cidx]);
      }
#pragma unroll
      for (int nj = 0; nj < 4; ++nj) {
        int row = wn * 64 + nj * 16 + lm;
        int cidx = (ks * 4 + lk) ^ (row & 7);
        bfv[nj] = *reinterpret_cast<const short8v*>(&lB[row * 8 + cidx]);
      }
#pragma unroll
      for (int mi = 0; mi < 4; ++mi)
#pragma unroll
        for (int nj = 0; nj < 4; ++nj)
          acc[mi][nj] = __builtin_amdgcn_mfma_f32_16x16x32_bf16(
              af[mi], bfv[nj], acc[mi][nj], 0, 0, 0);
    }
  }
  float bev[4];
#pragma unroll
  for (int nj = 0; nj < 4; ++nj)
    bev[nj] = be[e * NDIM + nbase + wn * 64 + nj * 16 + lm];
#pragma unroll
  for (int mi = 0; mi < 4; ++mi) {
#pragma unroll
    for (int r = 0; r < 4; ++r) {
      int grow = mbase + wm * 64 + mi * 16 + lk * 4 + r;
      if (grow >= cnt) continue;
      int tokn = lst[grow];
      float wgt = wl[grow];
      float* orow = out + (size_t)tokn * NDIM + nbase + wn * 64 + lm;
#pragma unroll
      for (int nj = 0; nj < 4; ++nj) {
        float val = wgt * (acc[mi][nj][r] + bev[nj]);
        if (ACCUM) orow[nj * 16] += val;
        else       orow[nj * 16] = val;
      }
    }
  }
}

// ============================ HOST ============================

extern "C" void kernel_launch(void* const* d_in, const int* in_sizes, int n_in,
                              void* d_out, int out_size, void* d_ws, size_t ws_size,
                              hipStream_t stream) {
  const float* x  = (const float*)d_in[0];
  const float* Wg = (const float*)d_in[1];
  const float* bg = (const float*)d_in[2];
  const float* We = (const float*)d_in[3];
  const float* be = (const float*)d_in[4];
  float* out = (float*)d_out;

  char* p = (char*)d_ws;
  int*   counts = (int*)p;                 p += 256;
  int*   lists  = (int*)p;                 p += (size_t)16 * TOKENS * 4;  // 512 KB
  float* wlists = (float*)p;               p += (size_t)16 * TOKENS * 4;  // 512 KB
  int*   epacked = (int*)p;                p += (size_t)TOKENS * 4;       // 32 KB
  float2* wpair  = (float2*)p;             p += (size_t)TOKENS * 8;       // 64 KB
  int*   hist    = (int*)p;                p += 256 * 16 * 4;             // 16 KB
  unsigned short* xbuf = (unsigned short*)p; p += (size_t)TOKENS * KDIM * 2;       // 16 MB
  unsigned short* Webf = (unsigned short*)p; p += (size_t)NEXP * NDIM * KDIM * 2;  // 16 MB
  size_t need_mid = (size_t)(p - (char*)d_ws);
  float* part1 = (float*)p;                p += (size_t)TOKENS * NDIM * 4;         // 32 MB
  size_t need_fast = (size_t)(p - (char*)d_ws);

  if (ws_size >= need_fast) {
    gate_conv_kernel<<<4352, 256, 0, stream>>>(
        x, Wg, bg, We, xbuf, Webf, epacked, wpair, hist, out);
    scatter_kernel<<<256, 256, 0, stream>>>(hist, epacked, wpair, counts, lists, wlists);
    // no-LDS barrier-free GEMM, XCD-pinned (id&7 = expert)
    moe_gemm_nolds<1><<<2048, 256, 0, stream>>>(
        xbuf, Webf, be, counts, lists, wlists, out, part1);
    combine_kernel<<<TOKENS * NDIM / 4 / 256, 256, 0, stream>>>(out, part1);
  } else if (ws_size >= need_mid) {
    gate_conv_kernel<<<5376, 256, 0, stream>>>(
        x, Wg, bg, We, xbuf, Webf, epacked, wpair, hist, out);
    scatter_kernel<<<256, 256, 0, stream>>>(hist, epacked, wpair, counts, lists, wlists);
    moe_gemm_wide<<<2048, 512, 0, stream>>>(
        xbuf, Webf, be, counts, lists, wlists, out);
  } else {
    dim3 grid(NDIM / 128, TOKENS / 128, NEXP);
    hipMemsetAsync(d_ws, 0, 64, stream);
    gate_kernel<<<TOKENS / 4, 256, 0, stream>>>(x, Wg, bg, counts, lists, wlists);
    moe_gemm<0><<<grid, 256, 0, stream>>>(x, We, be, counts, lists, wlists, out, 0);
    moe_gemm<1><<<grid, 256, 0, stream>>>(x, We, be, counts, lists, wlists, out, 1);
  }
}

// Round 19
// 111.366 us; speedup vs baseline: 1.9094x; 1.9094x over previous
//
#include <hip/hip_runtime.h>
#include <hip/hip_bf16.h>

#define TOKENS 8192
#define KDIM 1024
#define NDIM 1024
#define NEXP 8

typedef __attribute__((ext_vector_type(8))) short short8v;
typedef __attribute__((ext_vector_type(8))) unsigned short ushort8v;
typedef __attribute__((ext_vector_type(4))) float f32x4;

__device__ inline unsigned short f2bf(float f) {
  unsigned int u = __float_as_uint(f);
  u += 0x7fffu + ((u >> 16) & 1u);
  return (unsigned short)(u >> 16);
}

__device__ inline void gload_lds16(const void* g, void* l) {
  __builtin_amdgcn_global_load_lds(
      (const __attribute__((address_space(1))) unsigned int*)g,
      (__attribute__((address_space(3))) unsigned int*)l, 16, 0, 0);
}

// ============================ FAST PATH ============================

// Fused: [0,256) gating + x->bf16; [256,4352) We->bf16; [4352,5376) zero out
// (zero blocks only launched on the mid/atomic path).
__global__ __launch_bounds__(256) void gate_conv_kernel(
    const float* __restrict__ x, const float* __restrict__ Wg,
    const float* __restrict__ bg, const float* __restrict__ We,
    unsigned short* __restrict__ xb, unsigned short* __restrict__ Web,
    int* __restrict__ epacked, float2* __restrict__ wpair,
    int* __restrict__ hist, float* __restrict__ out) {
  int b = blockIdx.x;
  int tid = threadIdx.x;
  if (b >= 4352) {
    float4* o = reinterpret_cast<float4*>(out) + (size_t)(b - 4352) * 2048 + tid;
    float4 z = make_float4(0.f, 0.f, 0.f, 0.f);
#pragma unroll
    for (int i = 0; i < 8; ++i) o[i * 256] = z;
    return;
  }
  if (b >= 256) {
    size_t i = (size_t)(b - 256) * 256 + tid;
    const float4* s = reinterpret_cast<const float4*>(We + i * 8);
    float4 a = s[0], c = s[1];
    ushort8v v;
    v[0] = f2bf(a.x); v[1] = f2bf(a.y); v[2] = f2bf(a.z); v[3] = f2bf(a.w);
    v[4] = f2bf(c.x); v[5] = f2bf(c.y); v[6] = f2bf(c.z); v[7] = f2bf(c.w);
    *reinterpret_cast<ushort8v*>(Web + i * 8) = v;
    return;
  }
  __shared__ int lhist[16];
  if (tid < 16) lhist[tid] = 0;
  __syncthreads();
  int w = tid >> 6, lane = tid & 63;
  int tok0 = b * 32 + w * 8;

  for (int t = 0; t < 8; ++t) {
    int tok = tok0 + t;
    const float* xr = x + (size_t)tok * KDIM + lane * 16;
    float acc[NEXP] = {};
    ushort8v xv0, xv1;
#pragma unroll
    for (int j4 = 0; j4 < 4; ++j4) {
      float4 xv = *reinterpret_cast<const float4*>(xr + j4 * 4);
      float xs[4] = {xv.x, xv.y, xv.z, xv.w};
#pragma unroll
      for (int jj = 0; jj < 4; ++jj) {
        int k = lane * 16 + j4 * 4 + jj;
        const float4* wr = reinterpret_cast<const float4*>(Wg + k * NEXP);
        float4 w0 = wr[0], w1 = wr[1];
        float xf = xs[jj];
        acc[0] += xf * w0.x; acc[1] += xf * w0.y;
        acc[2] += xf * w0.z; acc[3] += xf * w0.w;
        acc[4] += xf * w1.x; acc[5] += xf * w1.y;
        acc[6] += xf * w1.z; acc[7] += xf * w1.w;
        int li = j4 * 4 + jj;
        unsigned short bv = f2bf(xf);
        if (li < 8) xv0[li] = bv; else xv1[li - 8] = bv;
      }
    }
    unsigned short* xrow = xb + (size_t)tok * KDIM + lane * 16;
    *reinterpret_cast<ushort8v*>(xrow) = xv0;
    *reinterpret_cast<ushort8v*>(xrow + 8) = xv1;
#pragma unroll
    for (int e = 0; e < NEXP; ++e) {
      acc[e] += __shfl_xor(acc[e], 1, 64);
      acc[e] += __shfl_xor(acc[e], 2, 64);
      acc[e] += __shfl_xor(acc[e], 4, 64);
      acc[e] += __shfl_xor(acc[e], 8, 64);
      acc[e] += __shfl_xor(acc[e], 16, 64);
      acc[e] += __shfl_xor(acc[e], 32, 64);
    }
    if (lane == 0) {
      float lg[NEXP];
#pragma unroll
      for (int e = 0; e < NEXP; ++e) lg[e] = acc[e] + bg[e];
      int e0 = 0;
#pragma unroll
      for (int e = 1; e < NEXP; ++e) if (lg[e] > lg[e0]) e0 = e;
      int e1 = -1;
#pragma unroll
      for (int e = 0; e < NEXP; ++e) {
        if (e == e0) continue;
        if (e1 < 0 || lg[e] > lg[e1]) e1 = e;
      }
      float tv = expf(lg[e1] - lg[e0]);
      float w0 = 1.0f / (1.0f + tv);
      float w1 = tv * w0;
      epacked[tok] = e0 | (e1 << 8);
      wpair[tok] = make_float2(w0, w1);
      atomicAdd(&lhist[e0], 1);
      atomicAdd(&lhist[8 + e1], 1);
    }
  }
  __syncthreads();
  if (tid < 16) hist[b * 16 + tid] = lhist[tid];
}

// scatter: per-block exclusive prefix over histograms -> routed lists.
__global__ __launch_bounds__(256) void scatter_kernel(
    const int* __restrict__ hist, const int* __restrict__ epacked,
    const float2* __restrict__ wpair, int* __restrict__ counts,
    int* __restrict__ lists, float* __restrict__ wlists) {
  __shared__ int partial[16][17];
  __shared__ int base[16];
  __shared__ int cnt2[16];
  int tid = threadIdx.x;
  int b = blockIdx.x;
  int bin = tid & 15, grp = tid >> 4;
  int s = 0;
  for (int i = 0; i < 16; ++i) {
    int bb = grp * 16 + i;
    if (bb < b) s += hist[bb * 16 + bin];
  }
  partial[grp][bin] = s;
  if (tid < 16) cnt2[tid] = 0;
  __syncthreads();
  if (tid < 16) {
    int s2 = 0;
#pragma unroll
    for (int g = 0; g < 16; ++g) s2 += partial[g][tid];
    base[tid] = s2;
  }
  __syncthreads();
  if (tid < 64) {
    int tok = b * 32 + (tid >> 1);
    int slot = tid & 1;
    int ep = epacked[tok];
    int e = slot ? ((ep >> 8) & 255) : (ep & 255);
    float2 wp = wpair[tok];
    float wv = slot ? wp.y : wp.x;
    int bn = slot * 8 + e;
    int pos = base[bn] + atomicAdd(&cnt2[bn], 1);
    lists[bn * TOKENS + pos] = tok;
    wlists[bn * TOKENS + pos] = wv;
  }
  if (b == 255) {
    __syncthreads();
    if (tid < 16) counts[tid] = base[tid] + cnt2[tid];
  }
}

// 128M x 256N x BK64 grouped GEMM = r14's proven body (512 thr / 8 waves
// 2Mx4N, wave 64x64 acc[4][4], VGPR 64, 48KB LDS -> 2 blocks/CU, serial
// 2-barrier loop, plain slot-split stores) + r17's flat XCD-pinned grid
// (id&7 = expert -> per-XCD B working set = one 2MB panel, L2-resident).
// WHY this composition: r17 proved FETCH irrelevant (99->39MB, no time
// change) -> LDS READ BW is the binder. LDS reads/FLOP ~ (1/Mw+1/Nw):
// wave 64x64 here = 2/3 the reads of r17's 32x64. Pinning removes r14's
// only downside (HBM B re-fetch).
template <int PLAIN>
__global__ __launch_bounds__(512) void moe_gemm_wide(
    const unsigned short* __restrict__ xb, const unsigned short* __restrict__ Web,
    const float* __restrict__ be, const int* __restrict__ counts,
    const int* __restrict__ lists, const float* __restrict__ wlists,
    float* __restrict__ out, float* __restrict__ p1) {
  int id = blockIdx.x;           // 1024 flat blocks
  int e = id & 7;                // XCD-pinned expert
  int rest = id >> 3;
  int slot = rest & 1;
  int bx = (rest >> 1) & 3;      // N-tile (256 wide)
  int by = rest >> 3;            // M-tile 0..15 (128 rows) -> 2048 cap
  int bz = slot * 8 + e;
  int cnt = counts[bz];
  int mbase = by * 128;
  if (mbase >= cnt) return;
  int nbase = bx * 256;
  const int* lst = lists + bz * TOKENS;
  const float* wl = wlists + bz * TOKENS;

  // single buffer; stored 16B-chunk cs at row r holds logical chunk cs^(r&7)
  __shared__ alignas(128) unsigned short lA[128 * 64];  // 16 KiB
  __shared__ alignas(128) unsigned short lB[256 * 64];  // 32 KiB

  int tid = threadIdx.x;         // 0..511
  int lane = tid & 63;
  int w = tid >> 6;              // wave 0..7
  int wm = w >> 2, wn = w & 3;   // 2M x 4N; wave output 64x64
  int lm = lane & 15, lk = lane >> 4;

  // A: 1024 chunks (128 rows x 8), 2/thread. B: 2048 chunks (256 rows x 8), 4/thread.
  const unsigned short* aga[2];
#pragma unroll
  for (int j = 0; j < 2; ++j) {
    int L = j * 512 + tid;
    int r = L >> 3, cs = L & 7;
    int c = cs ^ (r & 7);        // pre-swizzled source (rule 21)
    int gr = mbase + r; if (gr >= cnt) gr = cnt - 1;
    aga[j] = xb + (size_t)lst[gr] * KDIM + c * 8;
  }
  const unsigned short* bga[4];
#pragma unroll
  for (int j = 0; j < 4; ++j) {
    int L = j * 512 + tid;
    int r = L >> 3, cs = L & 7;
    int c = cs ^ (r & 7);
    bga[j] = Web + (size_t)e * (NDIM * KDIM) + (size_t)(nbase + r) * KDIM + c * 8;
  }

#define STAGE(kt)                                                             \
  {                                                                           \
    _Pragma("unroll") for (int j = 0; j < 2; ++j)                             \
      gload_lds16(aga[j] + (kt) * 64, (char*)lA + j * 8192 + w * 1024);       \
    _Pragma("unroll") for (int j = 0; j < 4; ++j)                             \
      gload_lds16(bga[j] + (kt) * 64, (char*)lB + j * 8192 + w * 1024);       \
  }

  f32x4 acc[4][4] = {};

#define COMPUTE                                                               \
  {                                                                           \
    _Pragma("unroll") for (int ks = 0; ks < 2; ++ks) {                        \
      short8v af[4], bfv[4];                                                  \
      _Pragma("unroll") for (int mi = 0; mi < 4; ++mi) {                      \
        int row = wm * 64 + mi * 16 + lm;                                     \
        int cs = (ks * 4 + lk) ^ (row & 7);                                   \
        af[mi] = *reinterpret_cast<const short8v*>(&lA[row * 64 + cs * 8]);   \
      }                                                                       \
      _Pragma("unroll") for (int nj = 0; nj < 4; ++nj) {                      \
        int row = wn * 64 + nj * 16 + lm;                                     \
        int cs = (ks * 4 + lk) ^ (row & 7);                                   \
        bfv[nj] = *reinterpret_cast<const short8v*>(&lB[row * 64 + cs * 8]);  \
      }                                                                       \
      _Pragma("unroll") for (int mi = 0; mi < 4; ++mi)                        \
        _Pragma("unroll") for (int nj = 0; nj < 4; ++nj)                      \
          acc[mi][nj] = __builtin_amdgcn_mfma_f32_16x16x32_bf16(              \
              af[mi], bfv[nj], acc[mi][nj], 0, 0, 0);                         \
    }                                                                         \
  }

  for (int kt = 0; kt < 16; ++kt) {
    __syncthreads();   // previous COMPUTE's ds_reads done before overwrite
    STAGE(kt);
    __syncthreads();   // drains vmcnt(0) before s_barrier -> tile ready
    COMPUTE;
  }
#undef STAGE
#undef COMPUTE

  // epilogue: C/D mapping col=lane&15, row=(lane>>4)*4+reg  [m89/m91]
  float* dst = (PLAIN && slot) ? p1 : out;
  float bev[4];
#pragma unroll
  for (int nj = 0; nj < 4; ++nj)
    bev[nj] = be[e * NDIM + nbase + wn * 64 + nj * 16 + lm];
#pragma unroll
  for (int mi = 0; mi < 4; ++mi) {
#pragma unroll
    for (int r = 0; r < 4; ++r) {
      int grow = mbase + wm * 64 + mi * 16 + lk * 4 + r;
      if (grow >= cnt) continue;
      int tokn = lst[grow];
      float wgt = wl[grow];
      float* orow = dst + (size_t)tokn * NDIM + nbase + wn * 64 + lm;
#pragma unroll
      for (int nj = 0; nj < 4; ++nj) {
        float val = wgt * (acc[mi][nj][r] + bev[nj]);
        if (PLAIN) orow[nj * 16] = val;
        else       unsafeAtomicAdd(&orow[nj * 16], val);
      }
    }
  }
}

// out += p1 (both full disjoint single-writer covers)
__global__ __launch_bounds__(256) void combine_kernel(
    float* __restrict__ out, const float* __restrict__ p1) {
  size_t i = (size_t)blockIdx.x * 256 + threadIdx.x;
  float4 a = reinterpret_cast<const float4*>(p1)[i];
  float4 b = reinterpret_cast<float4*>(out)[i];
  b.x += a.x; b.y += a.y; b.z += a.z; b.w += a.w;
  reinterpret_cast<float4*>(out)[i] = b;
}

// ============================ DEEP FALLBACK (round-1) ============================

__global__ __launch_bounds__(256) void gate_kernel(
    const float* __restrict__ x, const float* __restrict__ Wg,
    const float* __restrict__ bg, int* __restrict__ counts,
    int* __restrict__ lists, float* __restrict__ wlists) {
  int gtid = blockIdx.x * blockDim.x + threadIdx.x;
  int tok = gtid >> 6;
  int lane = threadIdx.x & 63;
  if (tok >= TOKENS) return;
  const float* xr = x + (size_t)tok * KDIM + lane * 16;
  float acc[NEXP] = {};
#pragma unroll
  for (int j4 = 0; j4 < 4; ++j4) {
    float4 xv = *reinterpret_cast<const float4*>(xr + j4 * 4);
    float xs[4] = {xv.x, xv.y, xv.z, xv.w};
#pragma unroll
    for (int jj = 0; jj < 4; ++jj) {
      int k = lane * 16 + j4 * 4 + jj;
      const float4* wr = reinterpret_cast<const float4*>(Wg + k * NEXP);
      float4 w0 = wr[0], w1 = wr[1];
      float xv1 = xs[jj];
      acc[0] += xv1 * w0.x; acc[1] += xv1 * w0.y;
      acc[2] += xv1 * w0.z; acc[3] += xv1 * w0.w;
      acc[4] += xv1 * w1.x; acc[5] += xv1 * w1.y;
      acc[6] += xv1 * w1.z; acc[7] += xv1 * w1.w;
    }
  }
#pragma unroll
  for (int e = 0; e < NEXP; ++e) {
    acc[e] += __shfl_xor(acc[e], 1, 64);
    acc[e] += __shfl_xor(acc[e], 2, 64);
    acc[e] += __shfl_xor(acc[e], 4, 64);
    acc[e] += __shfl_xor(acc[e], 8, 64);
    acc[e] += __shfl_xor(acc[e], 16, 64);
    acc[e] += __shfl_xor(acc[e], 32, 64);
  }
  if (lane == 0) {
    float lg[NEXP];
#pragma unroll
    for (int e = 0; e < NEXP; ++e) lg[e] = acc[e] + bg[e];
    int e0 = 0;
#pragma unroll
    for (int e = 1; e < NEXP; ++e) if (lg[e] > lg[e0]) e0 = e;
    int e1 = -1;
#pragma unroll
    for (int e = 0; e < NEXP; ++e) {
      if (e == e0) continue;
      if (e1 < 0 || lg[e] > lg[e1]) e1 = e;
    }
    float t = expf(lg[e1] - lg[e0]);
    float w0 = 1.0f / (1.0f + t);
    float w1 = t * w0;
    int p0 = atomicAdd(&counts[e0], 1);
    lists[e0 * TOKENS + p0] = tok;
    wlists[e0 * TOKENS + p0] = w0;
    int p1 = atomicAdd(&counts[NEXP + e1], 1);
    lists[(NEXP + e1) * TOKENS + p1] = tok;
    wlists[(NEXP + e1) * TOKENS + p1] = w1;
  }
}

template <int ACCUM>
__global__ __launch_bounds__(256) void moe_gemm(
    const float* __restrict__ x, const float* __restrict__ We,
    const float* __restrict__ be, const int* __restrict__ counts,
    const int* __restrict__ lists, const float* __restrict__ wlists,
    float* __restrict__ out, int slot) {
  int e = blockIdx.z;
  int cnt = counts[slot * NEXP + e];
  int mbase = blockIdx.y * 128;
  if (mbase >= cnt) return;
  int nbase = blockIdx.x * 128;
  const int* lst = lists + (slot * NEXP + e) * TOKENS;
  const float* wl = wlists + (slot * NEXP + e) * TOKENS;
  __shared__ ushort8v lA[1024];
  __shared__ ushort8v lB[1024];
  int tid = threadIdx.x;
  int lane = tid & 63;
  int w = tid >> 6;
  int wm = w >> 1, wn = w & 1;
  const float* aptr[4];
  const float* bptr[4];
  int sw[4];
#pragma unroll
  for (int i = 0; i < 4; ++i) {
    int c = i * 256 + tid;
    int r = c >> 3, cc = c & 7;
    int gr = mbase + r;
    if (gr >= cnt) gr = cnt - 1;
    int tokn = lst[gr];
    aptr[i] = x + (size_t)tokn * KDIM + cc * 8;
    bptr[i] = We + (size_t)e * (NDIM * KDIM) + (size_t)(nbase + r) * KDIM + cc * 8;
    sw[i] = r * 8 + (cc ^ (r & 7));
  }
  f32x4 acc[4][4] = {};
  int lm = lane & 15, lk = lane >> 4;
  for (int kt = 0; kt < KDIM / 64; ++kt) {
    __syncthreads();
#pragma unroll
    for (int i = 0; i < 4; ++i) {
      float4 f0 = *reinterpret_cast<const float4*>(aptr[i] + kt * 64);
      float4 f1 = *reinterpret_cast<const float4*>(aptr[i] + kt * 64 + 4);
      ushort8v v;
      v[0] = f2bf(f0.x); v[1] = f2bf(f0.y); v[2] = f2bf(f0.z); v[3] = f2bf(f0.w);
      v[4] = f2bf(f1.x); v[5] = f2bf(f1.y); v[6] = f2bf(f1.z); v[7] = f2bf(f1.w);
      lA[sw[i]] = v;
      float4 g0 = *reinterpret_cast<const float4*>(bptr[i] + kt * 64);
      float4 g1 = *reinterpret_cast<const float4*>(bptr[i] + kt * 64 + 4);
      ushort8v u;
      u[0] = f2bf(g0.x); u[1] = f2bf(g0.y); u[2] = f2bf(g0.z); u[3] = f2bf(g0.w);
      u[4] = f2bf(g1.x); u[5] = f2bf(g1.y); u[6] = f2bf(g1.z); u[7] = f2bf(g1.w);
      lB[sw[i]] = u;
    }
    __syncthreads();
#pragma unroll
    for (int ks = 0; ks < 2; ++ks) {
      short8v af[4], bfv[4];
#pragma unroll
      for (int mi = 0; mi < 4; ++mi) {
        int row = wm * 64 + mi * 16 + lm;
        int cidx = (ks * 4 + lk) ^ (row & 7);
        af[mi] = *reinterpret_cast<const short8v*>(&lA[row * 8 + cidx]);
      }
#pragma unroll
      for (int nj = 0; nj < 4; ++nj) {
        int row = wn * 64 + nj * 16 + lm;
        int cidx = (ks * 4 + lk) ^ (row & 7);
        bfv[nj] = *reinterpret_cast<const short8v*>(&lB[row * 8 + cidx]);
      }
#pragma unroll
      for (int mi = 0; mi < 4; ++mi)
#pragma unroll
        for (int nj = 0; nj < 4; ++nj)
          acc[mi][nj] = __builtin_amdgcn_mfma_f32_16x16x32_bf16(
              af[mi], bfv[nj], acc[mi][nj], 0, 0, 0);
    }
  }
  float bev[4];
#pragma unroll
  for (int nj = 0; nj < 4; ++nj)
    bev[nj] = be[e * NDIM + nbase + wn * 64 + nj * 16 + lm];
#pragma unroll
  for (int mi = 0; mi < 4; ++mi) {
#pragma unroll
    for (int r = 0; r < 4; ++r) {
      int grow = mbase + wm * 64 + mi * 16 + lk * 4 + r;
      if (grow >= cnt) continue;
      int tokn = lst[grow];
      float wgt = wl[grow];
      float* orow = out + (size_t)tokn * NDIM + nbase + wn * 64 + lm;
#pragma unroll
      for (int nj = 0; nj < 4; ++nj) {
        float val = wgt * (acc[mi][nj][r] + bev[nj]);
        if (ACCUM) orow[nj * 16] += val;
        else       orow[nj * 16] = val;
      }
    }
  }
}

// ============================ HOST ============================

extern "C" void kernel_launch(void* const* d_in, const int* in_sizes, int n_in,
                              void* d_out, int out_size, void* d_ws, size_t ws_size,
                              hipStream_t stream) {
  const float* x  = (const float*)d_in[0];
  const float* Wg = (const float*)d_in[1];
  const float* bg = (const float*)d_in[2];
  const float* We = (const float*)d_in[3];
  const float* be = (const float*)d_in[4];
  float* out = (float*)d_out;

  char* p = (char*)d_ws;
  int*   counts = (int*)p;                 p += 256;
  int*   lists  = (int*)p;                 p += (size_t)16 * TOKENS * 4;  // 512 KB
  float* wlists = (float*)p;               p += (size_t)16 * TOKENS * 4;  // 512 KB
  int*   epacked = (int*)p;                p += (size_t)TOKENS * 4;       // 32 KB
  float2* wpair  = (float2*)p;             p += (size_t)TOKENS * 8;       // 64 KB
  int*   hist    = (int*)p;                p += 256 * 16 * 4;             // 16 KB
  unsigned short* xbuf = (unsigned short*)p; p += (size_t)TOKENS * KDIM * 2;       // 16 MB
  unsigned short* Webf = (unsigned short*)p; p += (size_t)NEXP * NDIM * KDIM * 2;  // 16 MB
  size_t need_mid = (size_t)(p - (char*)d_ws);
  float* part1 = (float*)p;                p += (size_t)TOKENS * NDIM * 4;         // 32 MB
  size_t need_fast = (size_t)(p - (char*)d_ws);

  if (ws_size >= need_fast) {
    gate_conv_kernel<<<4352, 256, 0, stream>>>(
        x, Wg, bg, We, xbuf, Webf, epacked, wpair, hist, out);
    scatter_kernel<<<256, 256, 0, stream>>>(hist, epacked, wpair, counts, lists, wlists);
    // 1024 flat blocks: id&7 = expert (XCD-pinned B panel), 2 slots x 4 N x 16 M
    moe_gemm_wide<1><<<1024, 512, 0, stream>>>(
        xbuf, Webf, be, counts, lists, wlists, out, part1);
    combine_kernel<<<TOKENS * NDIM / 4 / 256, 256, 0, stream>>>(out, part1);
  } else if (ws_size >= need_mid) {
    gate_conv_kernel<<<5376, 256, 0, stream>>>(
        x, Wg, bg, We, xbuf, Webf, epacked, wpair, hist, out);
    scatter_kernel<<<256, 256, 0, stream>>>(hist, epacked, wpair, counts, lists, wlists);
    moe_gemm_wide<0><<<1024, 512, 0, stream>>>(
        xbuf, Webf, be, counts, lists, wlists, out, out);
  } else {
    dim3 grid(NDIM / 128, TOKENS / 128, NEXP);
    hipMemsetAsync(d_ws, 0, 64, stream);
    gate_kernel<<<TOKENS / 4, 256, 0, stream>>>(x, Wg, bg, counts, lists, wlists);
    moe_gemm<0><<<grid, 256, 0, stream>>>(x, We, be, counts, lists, wlists, out, 0);
    moe_gemm<1><<<grid, 256, 0, stream>>>(x, We, be, counts, lists, wlists, out, 1);
  }
}

// Round 20
// 105.387 us; speedup vs baseline: 2.0177x; 1.0567x over previous
//
#include <hip/hip_runtime.h>
#include <hip/hip_bf16.h>

#define TOKENS 8192
#define KDIM 1024
#define NDIM 1024
#define NEXP 8

typedef __attribute__((ext_vector_type(8))) short short8v;
typedef __attribute__((ext_vector_type(8))) unsigned short ushort8v;
typedef __attribute__((ext_vector_type(4))) float f32x4;

__device__ inline unsigned short f2bf(float f) {
  unsigned int u = __float_as_uint(f);
  u += 0x7fffu + ((u >> 16) & 1u);
  return (unsigned short)(u >> 16);
}

__device__ inline void gload_lds16(const void* g, void* l) {
  __builtin_amdgcn_global_load_lds(
      (const __attribute__((address_space(1))) unsigned int*)g,
      (__attribute__((address_space(3))) unsigned int*)l, 16, 0, 0);
}

// ============================ FAST PATH ============================

// Fused: [0,256) gating + x->bf16; [256,4352) We->bf16; [4352,5376) zero out
// (zero blocks only launched on the mid/atomic path).
__global__ __launch_bounds__(256) void gate_conv_kernel(
    const float* __restrict__ x, const float* __restrict__ Wg,
    const float* __restrict__ bg, const float* __restrict__ We,
    unsigned short* __restrict__ xb, unsigned short* __restrict__ Web,
    int* __restrict__ epacked, float2* __restrict__ wpair,
    int* __restrict__ hist, float* __restrict__ out) {
  int b = blockIdx.x;
  int tid = threadIdx.x;
  if (b >= 4352) {
    float4* o = reinterpret_cast<float4*>(out) + (size_t)(b - 4352) * 2048 + tid;
    float4 z = make_float4(0.f, 0.f, 0.f, 0.f);
#pragma unroll
    for (int i = 0; i < 8; ++i) o[i * 256] = z;
    return;
  }
  if (b >= 256) {
    size_t i = (size_t)(b - 256) * 256 + tid;
    const float4* s = reinterpret_cast<const float4*>(We + i * 8);
    float4 a = s[0], c = s[1];
    ushort8v v;
    v[0] = f2bf(a.x); v[1] = f2bf(a.y); v[2] = f2bf(a.z); v[3] = f2bf(a.w);
    v[4] = f2bf(c.x); v[5] = f2bf(c.y); v[6] = f2bf(c.z); v[7] = f2bf(c.w);
    *reinterpret_cast<ushort8v*>(Web + i * 8) = v;
    return;
  }
  __shared__ int lhist[16];
  if (tid < 16) lhist[tid] = 0;
  __syncthreads();
  int w = tid >> 6, lane = tid & 63;
  int tok0 = b * 32 + w * 8;

  for (int t = 0; t < 8; ++t) {
    int tok = tok0 + t;
    const float* xr = x + (size_t)tok * KDIM + lane * 16;
    float acc[NEXP] = {};
    ushort8v xv0, xv1;
#pragma unroll
    for (int j4 = 0; j4 < 4; ++j4) {
      float4 xv = *reinterpret_cast<const float4*>(xr + j4 * 4);
      float xs[4] = {xv.x, xv.y, xv.z, xv.w};
#pragma unroll
      for (int jj = 0; jj < 4; ++jj) {
        int k = lane * 16 + j4 * 4 + jj;
        const float4* wr = reinterpret_cast<const float4*>(Wg + k * NEXP);
        float4 w0 = wr[0], w1 = wr[1];
        float xf = xs[jj];
        acc[0] += xf * w0.x; acc[1] += xf * w0.y;
        acc[2] += xf * w0.z; acc[3] += xf * w0.w;
        acc[4] += xf * w1.x; acc[5] += xf * w1.y;
        acc[6] += xf * w1.z; acc[7] += xf * w1.w;
        int li = j4 * 4 + jj;
        unsigned short bv = f2bf(xf);
        if (li < 8) xv0[li] = bv; else xv1[li - 8] = bv;
      }
    }
    unsigned short* xrow = xb + (size_t)tok * KDIM + lane * 16;
    *reinterpret_cast<ushort8v*>(xrow) = xv0;
    *reinterpret_cast<ushort8v*>(xrow + 8) = xv1;
#pragma unroll
    for (int e = 0; e < NEXP; ++e) {
      acc[e] += __shfl_xor(acc[e], 1, 64);
      acc[e] += __shfl_xor(acc[e], 2, 64);
      acc[e] += __shfl_xor(acc[e], 4, 64);
      acc[e] += __shfl_xor(acc[e], 8, 64);
      acc[e] += __shfl_xor(acc[e], 16, 64);
      acc[e] += __shfl_xor(acc[e], 32, 64);
    }
    if (lane == 0) {
      float lg[NEXP];
#pragma unroll
      for (int e = 0; e < NEXP; ++e) lg[e] = acc[e] + bg[e];
      int e0 = 0;
#pragma unroll
      for (int e = 1; e < NEXP; ++e) if (lg[e] > lg[e0]) e0 = e;
      int e1 = -1;
#pragma unroll
      for (int e = 0; e < NEXP; ++e) {
        if (e == e0) continue;
        if (e1 < 0 || lg[e] > lg[e1]) e1 = e;
      }
      float tv = expf(lg[e1] - lg[e0]);
      float w0 = 1.0f / (1.0f + tv);
      float w1 = tv * w0;
      epacked[tok] = e0 | (e1 << 8);
      wpair[tok] = make_float2(w0, w1);
      atomicAdd(&lhist[e0], 1);
      atomicAdd(&lhist[8 + e1], 1);
    }
  }
  __syncthreads();
  if (tid < 16) hist[b * 16 + tid] = lhist[tid];
}

// scatter: per-block exclusive prefix over histograms -> routed lists.
__global__ __launch_bounds__(256) void scatter_kernel(
    const int* __restrict__ hist, const int* __restrict__ epacked,
    const float2* __restrict__ wpair, int* __restrict__ counts,
    int* __restrict__ lists, float* __restrict__ wlists) {
  __shared__ int partial[16][17];
  __shared__ int base[16];
  __shared__ int cnt2[16];
  int tid = threadIdx.x;
  int b = blockIdx.x;
  int bin = tid & 15, grp = tid >> 4;
  int s = 0;
  for (int i = 0; i < 16; ++i) {
    int bb = grp * 16 + i;
    if (bb < b) s += hist[bb * 16 + bin];
  }
  partial[grp][bin] = s;
  if (tid < 16) cnt2[tid] = 0;
  __syncthreads();
  if (tid < 16) {
    int s2 = 0;
#pragma unroll
    for (int g = 0; g < 16; ++g) s2 += partial[g][tid];
    base[tid] = s2;
  }
  __syncthreads();
  if (tid < 64) {
    int tok = b * 32 + (tid >> 1);
    int slot = tid & 1;
    int ep = epacked[tok];
    int e = slot ? ((ep >> 8) & 255) : (ep & 255);
    float2 wp = wpair[tok];
    float wv = slot ? wp.y : wp.x;
    int bn = slot * 8 + e;
    int pos = base[bn] + atomicAdd(&cnt2[bn], 1);
    lists[bn * TOKENS + pos] = tok;
    wlists[bn * TOKENS + pos] = wv;
  }
  if (b == 255) {
    __syncthreads();
    if (tid < 16) counts[tid] = base[tid] + cnt2[tid];
  }
}

// 128M x 256N x BK64 grouped GEMM (r19-proven body: 512 thr / 8 waves 2Mx4N,
// wave 64x64 acc[4][4], VGPR 64, 48KB LDS, serial 2-barrier loop, XCD-pinned
// flat grid id&7=expert).
// MODE 0: slot-0 dispatch, plain '=' stores to out.
// MODE 1: slot-1 dispatch, plain single-writer RMW 'out += val' (stream order
//         gives slot0->slot1 dependency; within the dispatch each element has
//         exactly one writer). Eliminates p1 + combine (~16us of traffic).
// MODE 2: atomic epilogue (mid path; out pre-zeroed; both slots, bz=blockIdx.z-style id).
template <int MODE>
__global__ __launch_bounds__(512) void moe_gemm_wide(
    const unsigned short* __restrict__ xb, const unsigned short* __restrict__ Web,
    const float* __restrict__ be, const int* __restrict__ counts,
    const int* __restrict__ lists, const float* __restrict__ wlists,
    float* __restrict__ out) {
  int id = blockIdx.x;           // 512 flat blocks (MODE 0/1), 1024 (MODE 2)
  int e = id & 7;                // XCD-pinned expert
  int rest = id >> 3;
  int slot, bx, by;
  if (MODE == 2) {
    slot = rest & 1;
    bx = (rest >> 1) & 3;
    by = rest >> 3;
  } else {
    slot = MODE;                 // dispatch-static slot
    bx = rest & 3;               // N-tile (256 wide)
    by = rest >> 2;              // M-tile 0..15 (128 rows) -> 2048 cap
  }
  int bz = slot * 8 + e;
  int cnt = counts[bz];
  int mbase = by * 128;
  if (mbase >= cnt) return;
  int nbase = bx * 256;
  const int* lst = lists + bz * TOKENS;
  const float* wl = wlists + bz * TOKENS;

  // single buffer; stored 16B-chunk cs at row r holds logical chunk cs^(r&7)
  __shared__ alignas(128) unsigned short lA[128 * 64];  // 16 KiB
  __shared__ alignas(128) unsigned short lB[256 * 64];  // 32 KiB

  int tid = threadIdx.x;         // 0..511
  int lane = tid & 63;
  int w = tid >> 6;              // wave 0..7
  int wm = w >> 2, wn = w & 3;   // 2M x 4N; wave output 64x64
  int lm = lane & 15, lk = lane >> 4;

  // A: 1024 chunks (128 rows x 8), 2/thread. B: 2048 chunks (256 rows x 8), 4/thread.
  const unsigned short* aga[2];
#pragma unroll
  for (int j = 0; j < 2; ++j) {
    int L = j * 512 + tid;
    int r = L >> 3, cs = L & 7;
    int c = cs ^ (r & 7);        // pre-swizzled source (rule 21)
    int gr = mbase + r; if (gr >= cnt) gr = cnt - 1;
    aga[j] = xb + (size_t)lst[gr] * KDIM + c * 8;
  }
  const unsigned short* bga[4];
#pragma unroll
  for (int j = 0; j < 4; ++j) {
    int L = j * 512 + tid;
    int r = L >> 3, cs = L & 7;
    int c = cs ^ (r & 7);
    bga[j] = Web + (size_t)e * (NDIM * KDIM) + (size_t)(nbase + r) * KDIM + c * 8;
  }

#define STAGE(kt)                                                             \
  {                                                                           \
    _Pragma("unroll") for (int j = 0; j < 2; ++j)                             \
      gload_lds16(aga[j] + (kt) * 64, (char*)lA + j * 8192 + w * 1024);       \
    _Pragma("unroll") for (int j = 0; j < 4; ++j)                             \
      gload_lds16(bga[j] + (kt) * 64, (char*)lB + j * 8192 + w * 1024);       \
  }

  f32x4 acc[4][4] = {};

#define COMPUTE                                                               \
  {                                                                           \
    _Pragma("unroll") for (int ks = 0; ks < 2; ++ks) {                        \
      short8v af[4], bfv[4];                                                  \
      _Pragma("unroll") for (int mi = 0; mi < 4; ++mi) {                      \
        int row = wm * 64 + mi * 16 + lm;                                     \
        int cs = (ks * 4 + lk) ^ (row & 7);                                   \
        af[mi] = *reinterpret_cast<const short8v*>(&lA[row * 64 + cs * 8]);   \
      }                                                                       \
      _Pragma("unroll") for (int nj = 0; nj < 4; ++nj) {                      \
        int row = wn * 64 + nj * 16 + lm;                                     \
        int cs = (ks * 4 + lk) ^ (row & 7);                                   \
        bfv[nj] = *reinterpret_cast<const short8v*>(&lB[row * 64 + cs * 8]);  \
      }                                                                       \
      _Pragma("unroll") for (int mi = 0; mi < 4; ++mi)                        \
        _Pragma("unroll") for (int nj = 0; nj < 4; ++nj)                      \
          acc[mi][nj] = __builtin_amdgcn_mfma_f32_16x16x32_bf16(              \
              af[mi], bfv[nj], acc[mi][nj], 0, 0, 0);                         \
    }                                                                         \
  }

  for (int kt = 0; kt < 16; ++kt) {
    __syncthreads();   // previous COMPUTE's ds_reads done before overwrite
    STAGE(kt);
    __syncthreads();   // drains vmcnt(0) before s_barrier -> tile ready
    COMPUTE;
  }
#undef STAGE
#undef COMPUTE

  // epilogue: C/D mapping col=lane&15, row=(lane>>4)*4+reg  [m89/m91]
  float bev[4];
#pragma unroll
  for (int nj = 0; nj < 4; ++nj)
    bev[nj] = be[e * NDIM + nbase + wn * 64 + nj * 16 + lm];
#pragma unroll
  for (int mi = 0; mi < 4; ++mi) {
#pragma unroll
    for (int r = 0; r < 4; ++r) {
      int grow = mbase + wm * 64 + mi * 16 + lk * 4 + r;
      if (grow >= cnt) continue;
      int tokn = lst[grow];
      float wgt = wl[grow];
      float* orow = out + (size_t)tokn * NDIM + nbase + wn * 64 + lm;
#pragma unroll
      for (int nj = 0; nj < 4; ++nj) {
        float val = wgt * (acc[mi][nj][r] + bev[nj]);
        if (MODE == 0)      orow[nj * 16] = val;
        else if (MODE == 1) orow[nj * 16] += val;   // single writer in this dispatch
        else                unsafeAtomicAdd(&orow[nj * 16], val);
      }
    }
  }
}

// ============================ DEEP FALLBACK (round-1) ============================

__global__ __launch_bounds__(256) void gate_kernel(
    const float* __restrict__ x, const float* __restrict__ Wg,
    const float* __restrict__ bg, int* __restrict__ counts,
    int* __restrict__ lists, float* __restrict__ wlists) {
  int gtid = blockIdx.x * blockDim.x + threadIdx.x;
  int tok = gtid >> 6;
  int lane = threadIdx.x & 63;
  if (tok >= TOKENS) return;
  const float* xr = x + (size_t)tok * KDIM + lane * 16;
  float acc[NEXP] = {};
#pragma unroll
  for (int j4 = 0; j4 < 4; ++j4) {
    float4 xv = *reinterpret_cast<const float4*>(xr + j4 * 4);
    float xs[4] = {xv.x, xv.y, xv.z, xv.w};
#pragma unroll
    for (int jj = 0; jj < 4; ++jj) {
      int k = lane * 16 + j4 * 4 + jj;
      const float4* wr = reinterpret_cast<const float4*>(Wg + k * NEXP);
      float4 w0 = wr[0], w1 = wr[1];
      float xv1 = xs[jj];
      acc[0] += xv1 * w0.x; acc[1] += xv1 * w0.y;
      acc[2] += xv1 * w0.z; acc[3] += xv1 * w0.w;
      acc[4] += xv1 * w1.x; acc[5] += xv1 * w1.y;
      acc[6] += xv1 * w1.z; acc[7] += xv1 * w1.w;
    }
  }
#pragma unroll
  for (int e = 0; e < NEXP; ++e) {
    acc[e] += __shfl_xor(acc[e], 1, 64);
    acc[e] += __shfl_xor(acc[e], 2, 64);
    acc[e] += __shfl_xor(acc[e], 4, 64);
    acc[e] += __shfl_xor(acc[e], 8, 64);
    acc[e] += __shfl_xor(acc[e], 16, 64);
    acc[e] += __shfl_xor(acc[e], 32, 64);
  }
  if (lane == 0) {
    float lg[NEXP];
#pragma unroll
    for (int e = 0; e < NEXP; ++e) lg[e] = acc[e] + bg[e];
    int e0 = 0;
#pragma unroll
    for (int e = 1; e < NEXP; ++e) if (lg[e] > lg[e0]) e0 = e;
    int e1 = -1;
#pragma unroll
    for (int e = 0; e < NEXP; ++e) {
      if (e == e0) continue;
      if (e1 < 0 || lg[e] > lg[e1]) e1 = e;
    }
    float t = expf(lg[e1] - lg[e0]);
    float w0 = 1.0f / (1.0f + t);
    float w1 = t * w0;
    int p0 = atomicAdd(&counts[e0], 1);
    lists[e0 * TOKENS + p0] = tok;
    wlists[e0 * TOKENS + p0] = w0;
    int p1 = atomicAdd(&counts[NEXP + e1], 1);
    lists[(NEXP + e1) * TOKENS + p1] = tok;
    wlists[(NEXP + e1) * TOKENS + p1] = w1;
  }
}

template <int ACCUM>
__global__ __launch_bounds__(256) void moe_gemm(
    const float* __restrict__ x, const float* __restrict__ We,
    const float* __restrict__ be, const int* __restrict__ counts,
    const int* __restrict__ lists, const float* __restrict__ wlists,
    float* __restrict__ out, int slot) {
  int e = blockIdx.z;
  int cnt = counts[slot * NEXP + e];
  int mbase = blockIdx.y * 128;
  if (mbase >= cnt) return;
  int nbase = blockIdx.x * 128;
  const int* lst = lists + (slot * NEXP + e) * TOKENS;
  const float* wl = wlists + (slot * NEXP + e) * TOKENS;
  __shared__ ushort8v lA[1024];
  __shared__ ushort8v lB[1024];
  int tid = threadIdx.x;
  int lane = tid & 63;
  int w = tid >> 6;
  int wm = w >> 1, wn = w & 1;
  const float* aptr[4];
  const float* bptr[4];
  int sw[4];
#pragma unroll
  for (int i = 0; i < 4; ++i) {
    int c = i * 256 + tid;
    int r = c >> 3, cc = c & 7;
    int gr = mbase + r;
    if (gr >= cnt) gr = cnt - 1;
    int tokn = lst[gr];
    aptr[i] = x + (size_t)tokn * KDIM + cc * 8;
    bptr[i] = We + (size_t)e * (NDIM * KDIM) + (size_t)(nbase + r) * KDIM + cc * 8;
    sw[i] = r * 8 + (cc ^ (r & 7));
  }
  f32x4 acc[4][4] = {};
  int lm = lane & 15, lk = lane >> 4;
  for (int kt = 0; kt < KDIM / 64; ++kt) {
    __syncthreads();
#pragma unroll
    for (int i = 0; i < 4; ++i) {
      float4 f0 = *reinterpret_cast<const float4*>(aptr[i] + kt * 64);
      float4 f1 = *reinterpret_cast<const float4*>(aptr[i] + kt * 64 + 4);
      ushort8v v;
      v[0] = f2bf(f0.x); v[1] = f2bf(f0.y); v[2] = f2bf(f0.z); v[3] = f2bf(f0.w);
      v[4] = f2bf(f1.x); v[5] = f2bf(f1.y); v[6] = f2bf(f1.z); v[7] = f2bf(f1.w);
      lA[sw[i]] = v;
      float4 g0 = *reinterpret_cast<const float4*>(bptr[i] + kt * 64);
      float4 g1 = *reinterpret_cast<const float4*>(bptr[i] + kt * 64 + 4);
      ushort8v u;
      u[0] = f2bf(g0.x); u[1] = f2bf(g0.y); u[2] = f2bf(g0.z); u[3] = f2bf(g0.w);
      u[4] = f2bf(g1.x); u[5] = f2bf(g1.y); u[6] = f2bf(g1.z); u[7] = f2bf(g1.w);
      lB[sw[i]] = u;
    }
    __syncthreads();
#pragma unroll
    for (int ks = 0; ks < 2; ++ks) {
      short8v af[4], bfv[4];
#pragma unroll
      for (int mi = 0; mi < 4; ++mi) {
        int row = wm * 64 + mi * 16 + lm;
        int cidx = (ks * 4 + lk) ^ (row & 7);
        af[mi] = *reinterpret_cast<const short8v*>(&lA[row * 8 + cidx]);
      }
#pragma unroll
      for (int nj = 0; nj < 4; ++nj) {
        int row = wn * 64 + nj * 16 + lm;
        int cidx = (ks * 4 + lk) ^ (row & 7);
        bfv[nj] = *reinterpret_cast<const short8v*>(&lB[row * 8 + cidx]);
      }
#pragma unroll
      for (int mi = 0; mi < 4; ++mi)
#pragma unroll
        for (int nj = 0; nj < 4; ++nj)
          acc[mi][nj] = __builtin_amdgcn_mfma_f32_16x16x32_bf16(
              af[mi], bfv[nj], acc[mi][nj], 0, 0, 0);
    }
  }
  float bev[4];
#pragma unroll
  for (int nj = 0; nj < 4; ++nj)
    bev[nj] = be[e * NDIM + nbase + wn * 64 + nj * 16 + lm];
#pragma unroll
  for (int mi = 0; mi < 4; ++mi) {
#pragma unroll
    for (int r = 0; r < 4; ++r) {
      int grow = mbase + wm * 64 + mi * 16 + lk * 4 + r;
      if (grow >= cnt) continue;
      int tokn = lst[grow];
      float wgt = wl[grow];
      float* orow = out + (size_t)tokn * NDIM + nbase + wn * 64 + lm;
#pragma unroll
      for (int nj = 0; nj < 4; ++nj) {
        float val = wgt * (acc[mi][nj][r] + bev[nj]);
        if (ACCUM) orow[nj * 16] += val;
        else       orow[nj * 16] = val;
      }
    }
  }
}

// ============================ HOST ============================

extern "C" void kernel_launch(void* const* d_in, const int* in_sizes, int n_in,
                              void* d_out, int out_size, void* d_ws, size_t ws_size,
                              hipStream_t stream) {
  const float* x  = (const float*)d_in[0];
  const float* Wg = (const float*)d_in[1];
  const float* bg = (const float*)d_in[2];
  const float* We = (const float*)d_in[3];
  const float* be = (const float*)d_in[4];
  float* out = (float*)d_out;

  char* p = (char*)d_ws;
  int*   counts = (int*)p;                 p += 256;
  int*   lists  = (int*)p;                 p += (size_t)16 * TOKENS * 4;  // 512 KB
  float* wlists = (float*)p;               p += (size_t)16 * TOKENS * 4;  // 512 KB
  int*   epacked = (int*)p;                p += (size_t)TOKENS * 4;       // 32 KB
  float2* wpair  = (float2*)p;             p += (size_t)TOKENS * 8;       // 64 KB
  int*   hist    = (int*)p;                p += 256 * 16 * 4;             // 16 KB
  unsigned short* xbuf = (unsigned short*)p; p += (size_t)TOKENS * KDIM * 2;       // 16 MB
  unsigned short* Webf = (unsigned short*)p; p += (size_t)NEXP * NDIM * KDIM * 2;  // 16 MB
  size_t need = (size_t)(p - (char*)d_ws);

  if (ws_size >= need) {
    gate_conv_kernel<<<4352, 256, 0, stream>>>(
        x, Wg, bg, We, xbuf, Webf, epacked, wpair, hist, out);
    scatter_kernel<<<256, 256, 0, stream>>>(hist, epacked, wpair, counts, lists, wlists);
    // slot 0: plain '=' stores; slot 1: plain '+=' RMW (stream-ordered dependency)
    moe_gemm_wide<0><<<512, 512, 0, stream>>>(
        xbuf, Webf, be, counts, lists, wlists, out);
    moe_gemm_wide<1><<<512, 512, 0, stream>>>(
        xbuf, Webf, be, counts, lists, wlists, out);
  } else {
    dim3 grid(NDIM / 128, TOKENS / 128, NEXP);
    hipMemsetAsync(d_ws, 0, 64, stream);
    gate_kernel<<<TOKENS / 4, 256, 0, stream>>>(x, Wg, bg, counts, lists, wlists);
    moe_gemm<0><<<grid, 256, 0, stream>>>(x, We, be, counts, lists, wlists, out, 0);
    moe_gemm<1><<<grid, 256, 0, stream>>>(x, We, be, counts, lists, wlists, out, 1);
  }
}